// Round 2
// baseline (435.210 us; speedup 1.0000x reference)
//
#include <hip/hip_runtime.h>

#define OUT 7
#define CCH 256

// ---------------- fallback (round-1) kernel: one thread per output elem ----
__global__ __launch_bounds__(256) void roi_pool_naive(
    const float* __restrict__ f0, const float* __restrict__ f1,
    const float* __restrict__ f2, const float* __restrict__ f3,
    const float* __restrict__ boxes, float* __restrict__ out,
    int M, int R)
{
    int idx = blockIdx.x * blockDim.x + threadIdx.x;
    int total = M * CCH * OUT * OUT;
    if (idx >= total) return;
    int pw = idx % OUT;
    int ph = (idx / OUT) % OUT;
    int c  = (idx / (OUT * OUT)) % CCH;
    int m  = idx / (OUT * OUT * CCH);
    int n  = m / R;
    const float bx1 = boxes[m * 4 + 0], by1 = boxes[m * 4 + 1];
    const float bx2 = boxes[m * 4 + 2], by2 = boxes[m * 4 + 3];
    float sz  = sqrtf(fmaxf((bx2 - bx1) * (by2 - by1), 0.0f));
    int lvl = (int)floorf(4.0f + log2f(sz / 224.0f + 1e-8f));
    lvl = min(max(lvl, 2), 5) - 2;
    const float* feat; int H, W; float scale;
    switch (lvl) {
        case 0:  feat = f0; H = 256; W = 256; scale = 0.25f;    break;
        case 1:  feat = f1; H = 128; W = 128; scale = 0.125f;   break;
        case 2:  feat = f2; H = 64;  W = 64;  scale = 0.0625f;  break;
        default: feat = f3; H = 32;  W = 32;  scale = 0.03125f; break;
    }
    const float* fp = feat + (size_t)(n * CCH + c) * (size_t)(H * W);
    float x1 = bx1 * scale - 0.5f, y1 = by1 * scale - 0.5f;
    float x2 = bx2 * scale - 0.5f, y2 = by2 * scale - 0.5f;
    float bw = (x2 - x1) * (1.0f / OUT), bh = (y2 - y1) * (1.0f / OUT);
    float acc = 0.0f;
    #pragma unroll
    for (int iy = 0; iy < 2; iy++) {
        float ys = y1 + ((float)ph + ((float)iy + 0.5f) * 0.5f) * bh;
        bool vy = (ys >= -1.0f) && (ys <= (float)H);
        float y = fminf(fmaxf(ys, 0.0f), (float)(H - 1));
        int y0 = (int)y;
        int y1i = min(y0 + 1, H - 1);
        float ly = y - (float)y0, hy = 1.0f - ly;
        #pragma unroll
        for (int ix = 0; ix < 2; ix++) {
            float xs = x1 + ((float)pw + ((float)ix + 0.5f) * 0.5f) * bw;
            bool vx = (xs >= -1.0f) && (xs <= (float)W);
            float x = fminf(fmaxf(xs, 0.0f), (float)(W - 1));
            int x0 = (int)x;
            int x1ii = min(x0 + 1, W - 1);
            float lx = x - (float)x0, hx = 1.0f - lx;
            if (vy && vx) {
                acc += hy * hx * fp[y0 * W + x0]  + hy * lx * fp[y0 * W + x1ii]
                     + ly * hx * fp[y1i * W + x0] + ly * lx * fp[y1i * W + x1ii];
            }
        }
    }
    out[idx] = acc * 0.25f;
}

// ---------------- NCHW -> NHWC transpose (per level), [C][HW] -> [HW][C] ----
__global__ __launch_bounds__(256) void transpose_cl(
    const float* __restrict__ in, float* __restrict__ outp, int HW)
{
    __shared__ float tile[32][33];
    int hw0 = blockIdx.x * 32;
    int c0  = blockIdx.y * 32;
    int n   = blockIdx.z;
    int tx = threadIdx.x, ty = threadIdx.y;   // (32, 8)
    const float* ib = in + (size_t)n * CCH * (size_t)HW;
    #pragma unroll
    for (int j = 0; j < 4; j++) {
        int c = c0 + ty + j * 8;
        tile[ty + j * 8][tx] = ib[(size_t)c * HW + hw0 + tx];
    }
    __syncthreads();
    float* ob = outp + (size_t)n * HW * CCH;
    #pragma unroll
    for (int j = 0; j < 4; j++) {
        int hw = hw0 + ty + j * 8;
        ob[(size_t)hw * CCH + c0 + tx] = tile[tx][ty + j * 8];
    }
}

// ---------------- main: one block per box, thread = channel -----------------
__global__ __launch_bounds__(256) void roi_pool_cl(
    const float* __restrict__ t0, const float* __restrict__ t1,
    const float* __restrict__ t2, const float* __restrict__ t3,
    const float* __restrict__ boxes, float* __restrict__ out, int R)
{
    __shared__ float lds[OUT * OUT * (CCH + 1)];
    int m = blockIdx.x;
    int t = threadIdx.x;          // channel
    int n = m / R;

    const float bx1 = boxes[m * 4 + 0], by1 = boxes[m * 4 + 1];
    const float bx2 = boxes[m * 4 + 2], by2 = boxes[m * 4 + 3];
    float sz  = sqrtf(fmaxf((bx2 - bx1) * (by2 - by1), 0.0f));
    int lvl = (int)floorf(4.0f + log2f(sz / 224.0f + 1e-8f));
    lvl = min(max(lvl, 2), 5) - 2;

    const float* feat; int H, W; float scale;
    switch (lvl) {
        case 0:  feat = t0; H = 256; W = 256; scale = 0.25f;    break;
        case 1:  feat = t1; H = 128; W = 128; scale = 0.125f;   break;
        case 2:  feat = t2; H = 64;  W = 64;  scale = 0.0625f;  break;
        default: feat = t3; H = 32;  W = 32;  scale = 0.03125f; break;
    }
    const float* fb = feat + (size_t)n * H * W * CCH;

    float x1 = bx1 * scale - 0.5f, y1 = by1 * scale - 0.5f;
    float x2 = bx2 * scale - 0.5f, y2 = by2 * scale - 0.5f;
    float bw = (x2 - x1) * (1.0f / OUT), bh = (y2 - y1) * (1.0f / OUT);

    for (int ph = 0; ph < OUT; ph++) {
        // two y-samples for this row of bins (wave-uniform)
        int   r0[2], r1[2];
        float lyv[2], hyv[2];
        bool  vyv[2];
        #pragma unroll
        for (int iy = 0; iy < 2; iy++) {
            float ys = y1 + ((float)ph + ((float)iy + 0.5f) * 0.5f) * bh;
            vyv[iy] = (ys >= -1.0f) && (ys <= (float)H);
            float y = fminf(fmaxf(ys, 0.0f), (float)(H - 1));
            int y0 = (int)y;
            int y1i = min(y0 + 1, H - 1);
            lyv[iy] = y - (float)y0;
            hyv[iy] = 1.0f - lyv[iy];
            r0[iy] = y0 * W * CCH;
            r1[iy] = y1i * W * CCH;
        }
        for (int pw = 0; pw < OUT; pw++) {
            int   c0i[2], c1i[2];
            float lxv[2], hxv[2];
            bool  vxv[2];
            #pragma unroll
            for (int ix = 0; ix < 2; ix++) {
                float xs = x1 + ((float)pw + ((float)ix + 0.5f) * 0.5f) * bw;
                vxv[ix] = (xs >= -1.0f) && (xs <= (float)W);
                float x = fminf(fmaxf(xs, 0.0f), (float)(W - 1));
                int x0 = (int)x;
                int x1i = min(x0 + 1, W - 1);
                lxv[ix] = x - (float)x0;
                hxv[ix] = 1.0f - lxv[ix];
                c0i[ix] = x0 * CCH;
                c1i[ix] = x1i * CCH;
            }
            float acc = 0.0f;
            #pragma unroll
            for (int iy = 0; iy < 2; iy++) {
                #pragma unroll
                for (int ix = 0; ix < 2; ix++) {
                    if (vyv[iy] && vxv[ix]) {
                        float v00 = fb[r0[iy] + c0i[ix] + t];
                        float v01 = fb[r0[iy] + c1i[ix] + t];
                        float v10 = fb[r1[iy] + c0i[ix] + t];
                        float v11 = fb[r1[iy] + c1i[ix] + t];
                        acc += hyv[iy] * (hxv[ix] * v00 + lxv[ix] * v01)
                             + lyv[iy] * (hxv[ix] * v10 + lxv[ix] * v11);
                    }
                }
            }
            lds[(ph * OUT + pw) * (CCH + 1) + t] = acc * 0.25f;
        }
    }
    __syncthreads();
    // write [C][49] for this box, linearly coalesced
    size_t ob = (size_t)m * CCH * (OUT * OUT);
    #pragma unroll 7
    for (int k = 0; k < OUT * OUT; k++) {
        int idx = k * CCH + t;
        int c   = idx / (OUT * OUT);
        int pix = idx % (OUT * OUT);
        out[ob + idx] = lds[pix * (CCH + 1) + c];
    }
}

extern "C" void kernel_launch(void* const* d_in, const int* in_sizes, int n_in,
                              void* d_out, int out_size, void* d_ws, size_t ws_size,
                              hipStream_t stream) {
    const float* f0    = (const float*)d_in[0];
    const float* f1    = (const float*)d_in[1];
    const float* f2    = (const float*)d_in[2];
    const float* f3    = (const float*)d_in[3];
    const float* boxes = (const float*)d_in[4];
    float* out = (float*)d_out;

    int N = in_sizes[0] / (CCH * 256 * 256);
    int M = in_sizes[4] / 4;
    int R = M / N;

    size_t nfloats = (size_t)N * CCH * (65536 + 16384 + 4096 + 1024);
    if (ws_size >= nfloats * sizeof(float)) {
        float* t0 = (float*)d_ws;
        float* t1 = t0 + (size_t)N * CCH * 65536;
        float* t2 = t1 + (size_t)N * CCH * 16384;
        float* t3 = t2 + (size_t)N * CCH * 4096;
        dim3 blk(32, 8);
        transpose_cl<<<dim3(65536 / 32, CCH / 32, N), blk, 0, stream>>>(f0, t0, 65536);
        transpose_cl<<<dim3(16384 / 32, CCH / 32, N), blk, 0, stream>>>(f1, t1, 16384);
        transpose_cl<<<dim3(4096  / 32, CCH / 32, N), blk, 0, stream>>>(f2, t2, 4096);
        transpose_cl<<<dim3(1024  / 32, CCH / 32, N), blk, 0, stream>>>(f3, t3, 1024);
        roi_pool_cl<<<M, 256, 0, stream>>>(t0, t1, t2, t3, boxes, out, R);
    } else {
        int total = M * CCH * OUT * OUT;
        roi_pool_naive<<<(total + 255) / 256, 256, 0, stream>>>(f0, f1, f2, f3, boxes, out, M, R);
    }
}

// Round 3
// 369.038 us; speedup vs baseline: 1.1793x; 1.1793x over previous
//
#include <hip/hip_runtime.h>

#define OUT 7
#define CCH 256

// ---------------- fallback: one thread per output elem (no ws needed) ------
__global__ __launch_bounds__(256) void roi_pool_naive(
    const float* __restrict__ f0, const float* __restrict__ f1,
    const float* __restrict__ f2, const float* __restrict__ f3,
    const float* __restrict__ boxes, float* __restrict__ out,
    int M, int R)
{
    int idx = blockIdx.x * blockDim.x + threadIdx.x;
    int total = M * CCH * OUT * OUT;
    if (idx >= total) return;
    int pw = idx % OUT;
    int ph = (idx / OUT) % OUT;
    int c  = (idx / (OUT * OUT)) % CCH;
    int m  = idx / (OUT * OUT * CCH);
    int n  = m / R;
    const float bx1 = boxes[m * 4 + 0], by1 = boxes[m * 4 + 1];
    const float bx2 = boxes[m * 4 + 2], by2 = boxes[m * 4 + 3];
    float sz  = sqrtf(fmaxf((bx2 - bx1) * (by2 - by1), 0.0f));
    int lvl = (int)floorf(4.0f + log2f(sz / 224.0f + 1e-8f));
    lvl = min(max(lvl, 2), 5) - 2;
    const float* feat; int H, W; float scale;
    switch (lvl) {
        case 0:  feat = f0; H = 256; W = 256; scale = 0.25f;    break;
        case 1:  feat = f1; H = 128; W = 128; scale = 0.125f;   break;
        case 2:  feat = f2; H = 64;  W = 64;  scale = 0.0625f;  break;
        default: feat = f3; H = 32;  W = 32;  scale = 0.03125f; break;
    }
    const float* fp = feat + (size_t)(n * CCH + c) * (size_t)(H * W);
    float x1 = bx1 * scale - 0.5f, y1 = by1 * scale - 0.5f;
    float x2 = bx2 * scale - 0.5f, y2 = by2 * scale - 0.5f;
    float bw = (x2 - x1) * (1.0f / OUT), bh = (y2 - y1) * (1.0f / OUT);
    float acc = 0.0f;
    #pragma unroll
    for (int iy = 0; iy < 2; iy++) {
        float ys = y1 + ((float)ph + ((float)iy + 0.5f) * 0.5f) * bh;
        bool vy = (ys >= -1.0f) && (ys <= (float)H);
        float y = fminf(fmaxf(ys, 0.0f), (float)(H - 1));
        int y0 = (int)y;
        int y1i = min(y0 + 1, H - 1);
        float ly = y - (float)y0, hy = 1.0f - ly;
        #pragma unroll
        for (int ix = 0; ix < 2; ix++) {
            float xs = x1 + ((float)pw + ((float)ix + 0.5f) * 0.5f) * bw;
            bool vx = (xs >= -1.0f) && (xs <= (float)W);
            float x = fminf(fmaxf(xs, 0.0f), (float)(W - 1));
            int x0 = (int)x;
            int x1ii = min(x0 + 1, W - 1);
            float lx = x - (float)x0, hx = 1.0f - lx;
            if (vy && vx) {
                acc += hy * hx * fp[y0 * W + x0]  + hy * lx * fp[y0 * W + x1ii]
                     + ly * hx * fp[y1i * W + x0] + ly * lx * fp[y1i * W + x1ii];
            }
        }
    }
    out[idx] = acc * 0.25f;
}

// ---- NCHW -> NHWC transpose, 64x64 tiles, float4 both sides ----------------
__global__ __launch_bounds__(256) void transpose_cl(
    const float* __restrict__ in, float* __restrict__ outp, int HW)
{
    __shared__ float tile[64][65];   // [c_local][hw_local], 65: 2-way aliasing only
    int hw0 = blockIdx.x * 64;
    int c0  = blockIdx.y * 64;
    int n   = blockIdx.z;
    int tx = threadIdx.x;   // 0..15 -> 4 floats along hw (load) / c (store)
    int ty = threadIdx.y;   // 0..15

    const float4* in4 = (const float4*)(in + (size_t)n * CCH * HW);
    #pragma unroll
    for (int j = 0; j < 4; j++) {
        int c = c0 + ty + 16 * j;
        float4 v = in4[((size_t)c * HW + hw0) / 4 + tx];
        tile[ty + 16 * j][4 * tx + 0] = v.x;
        tile[ty + 16 * j][4 * tx + 1] = v.y;
        tile[ty + 16 * j][4 * tx + 2] = v.z;
        tile[ty + 16 * j][4 * tx + 3] = v.w;
    }
    __syncthreads();
    float4* out4 = (float4*)(outp + (size_t)n * HW * CCH);
    #pragma unroll
    for (int j = 0; j < 4; j++) {
        int hw = hw0 + ty + 16 * j;
        float4 v;
        v.x = tile[4 * tx + 0][ty + 16 * j];
        v.y = tile[4 * tx + 1][ty + 16 * j];
        v.z = tile[4 * tx + 2][ty + 16 * j];
        v.w = tile[4 * tx + 3][ty + 16 * j];
        out4[((size_t)hw * CCH + c0) / 4 + tx] = v;
    }
}

// ---- main: one block per (box, ph); thread = channel -----------------------
__global__ __launch_bounds__(256) void roi_pool_cl(
    const float* __restrict__ t0, const float* __restrict__ t1,
    const float* __restrict__ t2, const float* __restrict__ t3,
    const float* __restrict__ boxes, float* __restrict__ out, int R)
{
    __shared__ float lds[OUT * 257];
    int bx = blockIdx.x;
    int m  = bx / OUT;
    int ph = bx % OUT;
    int t  = threadIdx.x;          // channel
    int n  = m / R;

    const float bx1 = boxes[m * 4 + 0], by1 = boxes[m * 4 + 1];
    const float bx2 = boxes[m * 4 + 2], by2 = boxes[m * 4 + 3];
    float sz  = sqrtf(fmaxf((bx2 - bx1) * (by2 - by1), 0.0f));
    int lvl = (int)floorf(4.0f + log2f(sz / 224.0f + 1e-8f));
    lvl = min(max(lvl, 2), 5) - 2;

    const float* feat; int H, W; float scale;
    switch (lvl) {
        case 0:  feat = t0; H = 256; W = 256; scale = 0.25f;    break;
        case 1:  feat = t1; H = 128; W = 128; scale = 0.125f;   break;
        case 2:  feat = t2; H = 64;  W = 64;  scale = 0.0625f;  break;
        default: feat = t3; H = 32;  W = 32;  scale = 0.03125f; break;
    }
    const float* fb = feat + (size_t)n * H * W * CCH;

    float x1 = bx1 * scale - 0.5f, y1 = by1 * scale - 0.5f;
    float x2 = bx2 * scale - 0.5f, y2 = by2 * scale - 0.5f;
    float bw = (x2 - x1) * (1.0f / OUT), bh = (y2 - y1) * (1.0f / OUT);

    // two y-samples for this bin row (block-uniform)
    int   r0[2], r1[2];
    float lyv[2], hyv[2];
    bool  vyv[2];
    #pragma unroll
    for (int iy = 0; iy < 2; iy++) {
        float ys = y1 + ((float)ph + ((float)iy + 0.5f) * 0.5f) * bh;
        vyv[iy] = (ys >= -1.0f) && (ys <= (float)H);
        float y = fminf(fmaxf(ys, 0.0f), (float)(H - 1));
        int y0 = (int)y;
        int y1i = min(y0 + 1, H - 1);
        lyv[iy] = y - (float)y0;
        hyv[iy] = 1.0f - lyv[iy];
        r0[iy] = y0 * W * CCH;
        r1[iy] = y1i * W * CCH;
    }

    #pragma unroll
    for (int pw = 0; pw < OUT; pw++) {
        float acc = 0.0f;
        #pragma unroll
        for (int ix = 0; ix < 2; ix++) {
            float xs = x1 + ((float)pw + ((float)ix + 0.5f) * 0.5f) * bw;
            bool vx = (xs >= -1.0f) && (xs <= (float)W);
            float x = fminf(fmaxf(xs, 0.0f), (float)(W - 1));
            int x0 = (int)x;
            int x1i = min(x0 + 1, W - 1);
            float lx = x - (float)x0;
            float hx = 1.0f - lx;
            int c0o = x0 * CCH;
            int c1o = x1i * CCH;
            #pragma unroll
            for (int iy = 0; iy < 2; iy++) {
                if (vyv[iy] && vx) {
                    // block-uniform offsets -> force scalar base, load = s[base]+v_t
                    const float* p00 = fb + __builtin_amdgcn_readfirstlane(r0[iy] + c0o);
                    const float* p01 = fb + __builtin_amdgcn_readfirstlane(r0[iy] + c1o);
                    const float* p10 = fb + __builtin_amdgcn_readfirstlane(r1[iy] + c0o);
                    const float* p11 = fb + __builtin_amdgcn_readfirstlane(r1[iy] + c1o);
                    float v00 = p00[t], v01 = p01[t], v10 = p10[t], v11 = p11[t];
                    acc += hyv[iy] * (hx * v00 + lx * v01)
                         + lyv[iy] * (hx * v10 + lx * v11);
                }
            }
        }
        lds[pw * 257 + t] = acc * 0.25f;
    }
    __syncthreads();

    // write this (box, ph)'s 256ch x 7pix slice; near-linear segments
    size_t ob = (size_t)m * CCH * (OUT * OUT) + ph * OUT;
    #pragma unroll
    for (int k = 0; k < OUT; k++) {
        int idx = k * 256 + t;       // 0..1791
        int c   = idx / OUT;
        int pix = idx % OUT;
        out[ob + (size_t)c * (OUT * OUT) + pix] = lds[pix * 257 + c];
    }
}

extern "C" void kernel_launch(void* const* d_in, const int* in_sizes, int n_in,
                              void* d_out, int out_size, void* d_ws, size_t ws_size,
                              hipStream_t stream) {
    const float* f0    = (const float*)d_in[0];
    const float* f1    = (const float*)d_in[1];
    const float* f2    = (const float*)d_in[2];
    const float* f3    = (const float*)d_in[3];
    const float* boxes = (const float*)d_in[4];
    float* out = (float*)d_out;

    int N = in_sizes[0] / (CCH * 256 * 256);
    int M = in_sizes[4] / 4;
    int R = M / N;

    size_t nfloats = (size_t)N * CCH * (65536 + 16384 + 4096 + 1024);
    if (ws_size >= nfloats * sizeof(float)) {
        float* t0 = (float*)d_ws;
        float* t1 = t0 + (size_t)N * CCH * 65536;
        float* t2 = t1 + (size_t)N * CCH * 16384;
        float* t3 = t2 + (size_t)N * CCH * 4096;
        dim3 blk(16, 16);
        transpose_cl<<<dim3(65536 / 64, CCH / 64, N), blk, 0, stream>>>(f0, t0, 65536);
        transpose_cl<<<dim3(16384 / 64, CCH / 64, N), blk, 0, stream>>>(f1, t1, 16384);
        transpose_cl<<<dim3(4096  / 64, CCH / 64, N), blk, 0, stream>>>(f2, t2, 4096);
        transpose_cl<<<dim3(1024  / 64, CCH / 64, N), blk, 0, stream>>>(f3, t3, 1024);
        roi_pool_cl<<<M * OUT, 256, 0, stream>>>(t0, t1, t2, t3, boxes, out, R);
    } else {
        int total = M * CCH * OUT * OUT;
        roi_pool_naive<<<(total + 255) / 256, 256, 0, stream>>>(f0, f1, f2, f3, boxes, out, M, R);
    }
}

// Round 4
// 312.773 us; speedup vs baseline: 1.3915x; 1.1799x over previous
//
#include <hip/hip_runtime.h>

#define OUT 7
#define CCH 256

__device__ __forceinline__ unsigned short f2bf(float f) {
    union { float f; unsigned int u; } v; v.f = f;
    unsigned int r = (v.u + 0x7FFFu + ((v.u >> 16) & 1u)) >> 16;   // RNE
    return (unsigned short)r;
}
__device__ __forceinline__ float bf2f(unsigned short h) {
    union { unsigned int u; float f; } v; v.u = ((unsigned int)h) << 16;
    return v.f;
}

// ---------------- fallback: one thread per output elem (no ws needed) ------
__global__ __launch_bounds__(256) void roi_pool_naive(
    const float* __restrict__ f0, const float* __restrict__ f1,
    const float* __restrict__ f2, const float* __restrict__ f3,
    const float* __restrict__ boxes, float* __restrict__ out,
    int M, int R)
{
    int idx = blockIdx.x * blockDim.x + threadIdx.x;
    int total = M * CCH * OUT * OUT;
    if (idx >= total) return;
    int pw = idx % OUT;
    int ph = (idx / OUT) % OUT;
    int c  = (idx / (OUT * OUT)) % CCH;
    int m  = idx / (OUT * OUT * CCH);
    int n  = m / R;
    const float bx1 = boxes[m * 4 + 0], by1 = boxes[m * 4 + 1];
    const float bx2 = boxes[m * 4 + 2], by2 = boxes[m * 4 + 3];
    float sz  = sqrtf(fmaxf((bx2 - bx1) * (by2 - by1), 0.0f));
    int lvl = (int)floorf(4.0f + log2f(sz / 224.0f + 1e-8f));
    lvl = min(max(lvl, 2), 5) - 2;
    const float* feat; int H, W; float scale;
    switch (lvl) {
        case 0:  feat = f0; H = 256; W = 256; scale = 0.25f;    break;
        case 1:  feat = f1; H = 128; W = 128; scale = 0.125f;   break;
        case 2:  feat = f2; H = 64;  W = 64;  scale = 0.0625f;  break;
        default: feat = f3; H = 32;  W = 32;  scale = 0.03125f; break;
    }
    const float* fp = feat + (size_t)(n * CCH + c) * (size_t)(H * W);
    float x1 = bx1 * scale - 0.5f, y1 = by1 * scale - 0.5f;
    float x2 = bx2 * scale - 0.5f, y2 = by2 * scale - 0.5f;
    float bw = (x2 - x1) * (1.0f / OUT), bh = (y2 - y1) * (1.0f / OUT);
    float acc = 0.0f;
    #pragma unroll
    for (int iy = 0; iy < 2; iy++) {
        float ys = y1 + ((float)ph + ((float)iy + 0.5f) * 0.5f) * bh;
        bool vy = (ys >= -1.0f) && (ys <= (float)H);
        float y = fminf(fmaxf(ys, 0.0f), (float)(H - 1));
        int y0 = (int)y;
        int y1i = min(y0 + 1, H - 1);
        float ly = y - (float)y0, hy = 1.0f - ly;
        #pragma unroll
        for (int ix = 0; ix < 2; ix++) {
            float xs = x1 + ((float)pw + ((float)ix + 0.5f) * 0.5f) * bw;
            bool vx = (xs >= -1.0f) && (xs <= (float)W);
            float x = fminf(fmaxf(xs, 0.0f), (float)(W - 1));
            int x0 = (int)x;
            int x1ii = min(x0 + 1, W - 1);
            float lx = x - (float)x0, hx = 1.0f - lx;
            if (vy && vx) {
                acc += hy * hx * fp[y0 * W + x0]  + hy * lx * fp[y0 * W + x1ii]
                     + ly * hx * fp[y1i * W + x0] + ly * lx * fp[y1i * W + x1ii];
            }
        }
    }
    out[idx] = acc * 0.25f;
}

// ---- NCHW fp32 -> NHWC bf16 transpose, 64x64 tiles -------------------------
__global__ __launch_bounds__(256) void transpose_bf16(
    const float* __restrict__ in, unsigned short* __restrict__ outp, int HW)
{
    __shared__ float tile[64][65];   // [c_local][hw_local]; 2-way alias = free
    int hw0 = blockIdx.x * 64;
    int c0  = blockIdx.y * 64;
    int n   = blockIdx.z;
    int tx = threadIdx.x;   // 0..15
    int ty = threadIdx.y;   // 0..15

    const float4* in4 = (const float4*)(in + (size_t)n * CCH * HW);
    #pragma unroll
    for (int j = 0; j < 4; j++) {
        int c = c0 + ty + 16 * j;
        float4 v = in4[((size_t)c * HW + hw0) / 4 + tx];
        tile[ty + 16 * j][4 * tx + 0] = v.x;
        tile[ty + 16 * j][4 * tx + 1] = v.y;
        tile[ty + 16 * j][4 * tx + 2] = v.z;
        tile[ty + 16 * j][4 * tx + 3] = v.w;
    }
    __syncthreads();
    unsigned short* ob = outp + (size_t)n * HW * CCH;
    #pragma unroll
    for (int j = 0; j < 4; j++) {
        int hw = hw0 + ty + 16 * j;
        ushort4 u;
        u.x = f2bf(tile[4 * tx + 0][ty + 16 * j]);
        u.y = f2bf(tile[4 * tx + 1][ty + 16 * j]);
        u.z = f2bf(tile[4 * tx + 2][ty + 16 * j]);
        u.w = f2bf(tile[4 * tx + 3][ty + 16 * j]);
        ((ushort4*)(ob + (size_t)hw * CCH + c0))[tx] = u;
    }
}

// ---- main: one block per (box, ph); thread = channel; no LDS ---------------
__global__ __launch_bounds__(256) void roi_pool_cl(
    const unsigned short* __restrict__ t0, const unsigned short* __restrict__ t1,
    const unsigned short* __restrict__ t2, const unsigned short* __restrict__ t3,
    const float* __restrict__ boxes, float* __restrict__ out, int M, int R)
{
    int bx = blockIdx.x;
    int m, ph;
    if ((M & 7) == 0) {
        // XCD swizzle: 56-block group = 8 boxes x 7 ph; a box's 7 blocks sit
        // 8 apart in dispatch order -> same XCD (round-robin heuristic) ->
        // partial-line output writes coalesce in that XCD's L2.
        int q = bx / 56, rem = bx - q * 56;
        ph = rem >> 3;
        m  = q * 8 + (rem & 7);
    } else {
        m = bx / OUT; ph = bx % OUT;
    }
    int t = threadIdx.x;          // channel
    int n = m / R;

    const float bx1 = boxes[m * 4 + 0], by1 = boxes[m * 4 + 1];
    const float bx2 = boxes[m * 4 + 2], by2 = boxes[m * 4 + 3];
    float sz  = sqrtf(fmaxf((bx2 - bx1) * (by2 - by1), 0.0f));
    int lvl = (int)floorf(4.0f + log2f(sz / 224.0f + 1e-8f));
    lvl = min(max(lvl, 2), 5) - 2;

    const unsigned short* feat; int H, W; float scale;
    switch (lvl) {
        case 0:  feat = t0; H = 256; W = 256; scale = 0.25f;    break;
        case 1:  feat = t1; H = 128; W = 128; scale = 0.125f;   break;
        case 2:  feat = t2; H = 64;  W = 64;  scale = 0.0625f;  break;
        default: feat = t3; H = 32;  W = 32;  scale = 0.03125f; break;
    }
    const unsigned short* fb = feat + (size_t)n * H * W * CCH;

    float x1 = bx1 * scale - 0.5f, y1 = by1 * scale - 0.5f;
    float x2 = bx2 * scale - 0.5f, y2 = by2 * scale - 0.5f;
    float bw = (x2 - x1) * (1.0f / OUT), bh = (y2 - y1) * (1.0f / OUT);

    // two y-samples for this bin row (block-uniform)
    int   r0[2], r1[2];
    float lyv[2], hyv[2];
    bool  vyv[2];
    #pragma unroll
    for (int iy = 0; iy < 2; iy++) {
        float ys = y1 + ((float)ph + ((float)iy + 0.5f) * 0.5f) * bh;
        vyv[iy] = (ys >= -1.0f) && (ys <= (float)H);
        float y = fminf(fmaxf(ys, 0.0f), (float)(H - 1));
        int y0 = (int)y;
        int y1i = min(y0 + 1, H - 1);
        lyv[iy] = y - (float)y0;
        hyv[iy] = 1.0f - lyv[iy];
        r0[iy] = y0 * W * CCH;
        r1[iy] = y1i * W * CCH;
    }

    float acc[OUT];
    #pragma unroll
    for (int pw = 0; pw < OUT; pw++) {
        float a = 0.0f;
        #pragma unroll
        for (int ix = 0; ix < 2; ix++) {
            float xs = x1 + ((float)pw + ((float)ix + 0.5f) * 0.5f) * bw;
            bool vx = (xs >= -1.0f) && (xs <= (float)W);
            float x = fminf(fmaxf(xs, 0.0f), (float)(W - 1));
            int x0 = (int)x;
            int x1i = min(x0 + 1, W - 1);
            float lx = x - (float)x0;
            float hx = 1.0f - lx;
            int c0o = x0 * CCH;
            int c1o = x1i * CCH;
            #pragma unroll
            for (int iy = 0; iy < 2; iy++) {
                if (vyv[iy] && vx) {
                    const unsigned short* p00 = fb + __builtin_amdgcn_readfirstlane(r0[iy] + c0o);
                    const unsigned short* p01 = fb + __builtin_amdgcn_readfirstlane(r0[iy] + c1o);
                    const unsigned short* p10 = fb + __builtin_amdgcn_readfirstlane(r1[iy] + c0o);
                    const unsigned short* p11 = fb + __builtin_amdgcn_readfirstlane(r1[iy] + c1o);
                    float v00 = bf2f(p00[t]), v01 = bf2f(p01[t]);
                    float v10 = bf2f(p10[t]), v11 = bf2f(p11[t]);
                    a += hyv[iy] * (hx * v00 + lx * v01)
                       + lyv[iy] * (hx * v10 + lx * v11);
                }
            }
        }
        acc[pw] = a * 0.25f;
    }

    // thread t owns channel t's 7 values for this ph row: contiguous 28 B
    float* ob = out + (size_t)m * (CCH * OUT * OUT) + (size_t)t * (OUT * OUT) + ph * OUT;
    #pragma unroll
    for (int k = 0; k < OUT; k++) ob[k] = acc[k];
}

extern "C" void kernel_launch(void* const* d_in, const int* in_sizes, int n_in,
                              void* d_out, int out_size, void* d_ws, size_t ws_size,
                              hipStream_t stream) {
    const float* f0    = (const float*)d_in[0];
    const float* f1    = (const float*)d_in[1];
    const float* f2    = (const float*)d_in[2];
    const float* f3    = (const float*)d_in[3];
    const float* boxes = (const float*)d_in[4];
    float* out = (float*)d_out;

    int N = in_sizes[0] / (CCH * 256 * 256);
    int M = in_sizes[4] / 4;
    int R = M / N;

    size_t nshorts = (size_t)N * CCH * (65536 + 16384 + 4096 + 1024);
    if (ws_size >= nshorts * sizeof(unsigned short)) {
        unsigned short* t0 = (unsigned short*)d_ws;
        unsigned short* t1 = t0 + (size_t)N * CCH * 65536;
        unsigned short* t2 = t1 + (size_t)N * CCH * 16384;
        unsigned short* t3 = t2 + (size_t)N * CCH * 4096;
        dim3 blk(16, 16);
        transpose_bf16<<<dim3(65536 / 64, CCH / 64, N), blk, 0, stream>>>(f0, t0, 65536);
        transpose_bf16<<<dim3(16384 / 64, CCH / 64, N), blk, 0, stream>>>(f1, t1, 16384);
        transpose_bf16<<<dim3(4096  / 64, CCH / 64, N), blk, 0, stream>>>(f2, t2, 4096);
        transpose_bf16<<<dim3(1024  / 64, CCH / 64, N), blk, 0, stream>>>(f3, t3, 1024);
        roi_pool_cl<<<M * OUT, 256, 0, stream>>>(t0, t1, t2, t3, boxes, out, M, R);
    } else {
        int total = M * CCH * OUT * OUT;
        roi_pool_naive<<<(total + 255) / 256, 256, 0, stream>>>(f0, f1, f2, f3, boxes, out, M, R);
    }
}